// Round 15
// baseline (120.542 us; speedup 1.0000x reference)
//
#include <hip/hip_runtime.h>
#include <math.h>

// S4 block: fused-head (Cauchy + W-convert), fused-mid (Kd FFT + u-transpose),
// s4_conv (reg FFTs + Kd-prefetch + collapsed pointwise + skip+GELU -> bf16
// overlay), MFMA GEMM+LN (double-buffered staging).  B=8, L=4096, D=256, N=64.

typedef __attribute__((ext_vector_type(2))) float cf;
typedef __attribute__((ext_vector_type(8))) short bf16x8;
typedef __attribute__((ext_vector_type(4))) float f32x4;

__device__ __forceinline__ cf mkcf(float x, float y){ cf r; r.x = x; r.y = y; return r; }

__device__ __forceinline__ cf cadd(cf a, cf b){ return a + b; }       // v_pk_add_f32
__device__ __forceinline__ cf csub(cf a, cf b){ return a - b; }
__device__ __forceinline__ cf cscale(cf a, float s){ return a * s; }  // v_pk_mul_f32
__device__ __forceinline__ cf cconj(cf a){ return mkcf(a.x, -a.y); }
__device__ __forceinline__ cf cmul(cf a, cf b){                       // scalar 4-fma
  return mkcf(fmaf(a.x, b.x, -a.y*b.y), fmaf(a.x, b.y, a.y*b.x));
}
// acc += a*b, fused (4 fma)
__device__ __forceinline__ void cmacc(cf& acc, cf a, cf b){
  acc.x = fmaf(a.x, b.x, fmaf(-a.y, b.y, acc.x));
  acc.y = fmaf(a.x, b.y, fmaf( a.y, b.x, acc.y));
}

__device__ __forceinline__ short f2bf(float x){   // RNE float->bf16
  union { float f; unsigned u; } v; v.f = x;
  unsigned r = v.u + 0x7fffu + ((v.u >> 16) & 1u);
  return (short)(r >> 16);
}

__device__ __forceinline__ constexpr int RI(int k){ return ((k & 3) << 2) | (k >> 2); }

#define C8 0.92387953251f
#define S8 0.38268343236f
#define RH 0.70710678119f

template<int DIR>
__device__ __forceinline__ void r4(cf& a, cf& b, cf& c, cf& d){
  cf T0 = a + c, T1 = a - c;
  cf T2 = b + d, Bd = b - d;
  a = T0 + T2; c = T0 - T2;
  cf iBd = (DIR > 0) ? mkcf(-Bd.y, Bd.x) : mkcf(Bd.y, -Bd.x);   // ±i*Bd
  b = T1 + iBd; d = T1 - iBd;
}

// FFT16; if HZ, inputs v[8..15] are known zero (stage-1 r4s degenerate).
template<int DIR, bool HZ>
__device__ __forceinline__ void fft16(cf* v){
  if constexpr (HZ){
    #pragma unroll
    for (int i = 0; i < 4; ++i){
      cf a = v[i], b = v[i+4];
      cf ib = (DIR > 0) ? mkcf(-b.y, b.x) : mkcf(b.y, -b.x);
      v[i]    = a + b;
      v[i+8]  = a - b;
      v[i+4]  = a + ib;
      v[i+12] = a - ib;
    }
  } else {
    r4<DIR>(v[0], v[4], v[8],  v[12]);
    r4<DIR>(v[1], v[5], v[9],  v[13]);
    r4<DIR>(v[2], v[6], v[10], v[14]);
    r4<DIR>(v[3], v[7], v[11], v[15]);
  }
  constexpr float D = (float)DIR;
  const cf w1 = mkcf(C8,  D*S8);
  const cf w2 = mkcf(RH,  D*RH);
  const cf w3 = mkcf(S8,  D*C8);
  const cf w6 = mkcf(-RH, D*RH);
  const cf w9 = mkcf(-C8, -D*S8);
  v[5]  = cmul(v[5],  w1);
  v[6]  = cmul(v[6],  w2);
  v[7]  = cmul(v[7],  w3);
  v[9]  = cmul(v[9],  w2);
  v[10] = (DIR > 0) ? mkcf(-v[10].y, v[10].x) : mkcf(v[10].y, -v[10].x);
  v[11] = cmul(v[11], w6);
  v[13] = cmul(v[13], w3);
  v[14] = cmul(v[14], w6);
  v[15] = cmul(v[15], w9);
  r4<DIR>(v[0],  v[1],  v[2],  v[3]);
  r4<DIR>(v[4],  v[5],  v[6],  v[7]);
  r4<DIR>(v[8],  v[9],  v[10], v[11]);
  r4<DIR>(v[12], v[13], v[14], v[15]);
}

// 4096-pt FFT, four-step 16x(16x16).  Entry: v[n1] = x[n1*256 + t].
// Exit: V[k1+16*ka+256*kb] = v[RI(kb)], k1 = t>>4, ka = t&15.
template<int DIR, bool HZ = false>
__device__ void fft4096_reg(cf* v, cf* lds){
  const int t = threadIdx.x;
  const int k1 = t >> 4, m2 = t & 15;
  const int swt = t ^ k1;
  constexpr float D = (float)DIR;
  fft16<DIR, HZ>(v);
  float sn, cs;
  __sincosf(D * 1.5339807878856412e-3f * (float)t, &sn, &cs);   // 2pi/4096
  __syncthreads();
  {
    cf* p = lds + swt;
    cf w1 = mkcf(cs, sn);
    p[0]    = v[0];
    p[256]  = cmul(v[RI(1)],  w1);
    cf w2 = cmul(w1, w1);
    p[512]  = cmul(v[RI(2)],  w2);
    cf w3 = cmul(w2, w1);
    p[768]  = cmul(v[RI(3)],  w3);
    cf w4 = cmul(w2, w2);
    p[1024] = cmul(v[RI(4)],  w4);
    cf w5 = cmul(w4, w1);
    p[1280] = cmul(v[RI(5)],  w5);
    cf w6 = cmul(w4, w2);
    p[1536] = cmul(v[RI(6)],  w6);
    cf w7 = cmul(w4, w3);
    p[1792] = cmul(v[RI(7)],  w7);
    cf w8 = cmul(w4, w4);
    p[2048] = cmul(v[RI(8)],  w8);
    p[2304] = cmul(v[RI(9)],  cmul(w8, w1));
    p[2560] = cmul(v[RI(10)], cmul(w8, w2));
    p[2816] = cmul(v[RI(11)], cmul(w8, w3));
    p[3072] = cmul(v[RI(12)], cmul(w8, w4));
    p[3328] = cmul(v[RI(13)], cmul(w8, w5));
    p[3584] = cmul(v[RI(14)], cmul(w8, w6));
    p[3840] = cmul(v[RI(15)], cmul(w8, w7));
  }
  __syncthreads();
  {
    cf* p = lds + k1*256;
    #pragma unroll
    for (int m1 = 0; m1 < 16; ++m1) v[m1] = p[m1*16 + (m2 ^ m1)];
  }
  fft16<DIR, false>(v);
  __sincosf(D * 2.45436926061703e-2f * (float)m2, &sn, &cs);    // 2pi/256
  __syncthreads();
  {
    cf* p = lds + k1*256;
    cf w1 = mkcf(cs, sn);
    p[m2]              = v[0];
    p[16  + (m2^1)]    = cmul(v[RI(1)],  w1);
    cf w2 = cmul(w1, w1);
    p[32  + (m2^2)]    = cmul(v[RI(2)],  w2);
    cf w3 = cmul(w2, w1);
    p[48  + (m2^3)]    = cmul(v[RI(3)],  w3);
    cf w4 = cmul(w2, w2);
    p[64  + (m2^4)]    = cmul(v[RI(4)],  w4);
    cf w5 = cmul(w4, w1);
    p[80  + (m2^5)]    = cmul(v[RI(5)],  w5);
    cf w6 = cmul(w4, w2);
    p[96  + (m2^6)]    = cmul(v[RI(6)],  w6);
    cf w7 = cmul(w4, w3);
    p[112 + (m2^7)]    = cmul(v[RI(7)],  w7);
    cf w8 = cmul(w4, w4);
    p[128 + (m2^8)]    = cmul(v[RI(8)],  w8);
    p[144 + (m2^9)]    = cmul(v[RI(9)],  cmul(w8, w1));
    p[160 + (m2^10)]   = cmul(v[RI(10)], cmul(w8, w2));
    p[176 + (m2^11)]   = cmul(v[RI(11)], cmul(w8, w3));
    p[192 + (m2^12)]   = cmul(v[RI(12)], cmul(w8, w4));
    p[208 + (m2^13)]   = cmul(v[RI(13)], cmul(w8, w5));
    p[224 + (m2^14)]   = cmul(v[RI(14)], cmul(w8, w6));
    p[240 + (m2^15)]   = cmul(v[RI(15)], cmul(w8, w7));
  }
  __syncthreads();
  {
    const int ka = m2;
    cf* p = lds + k1*256 + ka*16;
    #pragma unroll
    for (int m2b = 0; m2b < 16; ++m2b) v[m2b] = p[m2b ^ ka];
  }
  fft16<DIR, false>(v);
}

// ---------------------------------------------------------------------------
// fused_head: blocks [0,2048) = Cauchy (Hermitian half -> KdE even bins);
// blocks [2048,2112) = W f32->bf16 fragment-major.
__global__ __launch_bounds__(256)
void fused_head(const float* __restrict__ B_ri, const float* __restrict__ Ct_ri,
                const float* __restrict__ lam_ri, const float* __restrict__ p_ri,
                const float* __restrict__ q_ri, const float* __restrict__ log_step,
                float* __restrict__ KdE,
                const float* __restrict__ W, short* __restrict__ Wbf){
  __shared__ cf w00[64], w01[64], w10[64], w11[64], lamS[64];
  const int bid = blockIdx.x;
  const int tid = threadIdx.x;

  if (bid >= 2048){
    int t  = (bid - 2048) * 256 + tid;          // 16384 threads
    int o4 = t * 4;
    int j   = o4 & 7;
    int lm  = (o4 >> 3)  & 15;
    int lk  = (o4 >> 7)  & 3;
    int nt  = (o4 >> 9)  & 7;
    int fh2 = (o4 >> 12) & 1;
    int ks  = o4 >> 13;
    int f = fh2*128 + nt*16 + lm;
    int k = ks*32 + lk*8 + j;
    float4 wv = *(const float4*)(W + (size_t)f*256 + k);
    short4 o;
    o.x = f2bf(wv.x); o.y = f2bf(wv.y); o.z = f2bf(wv.z); o.w = f2bf(wv.w);
    *(short4*)(Wbf + o4) = o;
    return;
  }

  const int d     = bid >> 3;
  const int chunk = bid & 7;
  const float step = expf(log_step[d]);

  if (tid < 64){
    int n = tid;
    cf Bv = mkcf(B_ri[(d*64+n)*2],  B_ri[(d*64+n)*2+1]);
    cf Cv = mkcf(Ct_ri[(d*64+n)*2], Ct_ri[(d*64+n)*2+1]);
    cf pv = mkcf(p_ri[n*2], p_ri[n*2+1]);
    cf qv = mkcf(q_ri[n*2], q_ri[n*2+1]);
    lamS[n] = mkcf(lam_ri[n*2], lam_ri[n*2+1]);
    cf Cc = cconj(Cv), qc = cconj(qv);
    w00[n] = cmul(Cc, Bv);
    w01[n] = cmul(Cc, pv);
    w10[n] = cmul(qc, Bv);
    w11[n] = cmul(qc, pv);
  }
  __syncthreads();

  cf* out = (cf*)KdE + (size_t)d * 2049;
  const int l = chunk * 256 + tid;               // 0..2047
  {
    float th = -(6.28318530717958647692f * (float)l) * (1.0f/4096.0f);
    float sn, cs; __sincosf(th, &sn, &cs);
    cf opw = mkcf(1.0f + cs,  sn);               // 1 + omega
    cf omw = mkcf(1.0f - cs, -sn);               // 1 - omega
    float idn = __builtin_amdgcn_rcpf(fmaf(opw.x, opw.x, opw.y*opw.y));
    cf ratio = mkcf((omw.x*opw.x + omw.y*opw.y)*idn,
                    (omw.y*opw.x - omw.x*opw.y)*idn);
    cf g  = cscale(ratio, 2.0f / step);
    cf cc = mkcf(2.0f*opw.x*idn, -2.0f*opw.y*idn);   // 2/(1+omega)
    cf k00 = mkcf(0,0), k01 = mkcf(0,0), k10 = mkcf(0,0), k11 = mkcf(0,0);
    #pragma unroll 4
    for (int n = 0; n < 64; ++n){
      cf den = g - lamS[n];
      float is = __builtin_amdgcn_rcpf(fmaf(den.x, den.x, den.y*den.y));
      cf r = mkcf(den.x*is, -den.y*is);              // 1/(g - lam)
      cmacc(k00, w00[n], r);
      cmacc(k01, w01[n], r);
      cmacc(k10, w10[n], r);
      cmacc(k11, w11[n], r);
    }
    cf onep = mkcf(1.0f + k11.x, k11.y);
    float ii = __builtin_amdgcn_rcpf(fmaf(onep.x, onep.x, onep.y*onep.y));
    cf inv1p = mkcf(onep.x*ii, -onep.y*ii);
    cf corr = cmul(k01, cmul(k10, inv1p));
    out[l] = cmul(cc, csub(k00, corr));
  }
  if (chunk == 7 && tid == 255){
    cf s00 = mkcf(0.f, 0.f);
    for (int n = 0; n < 64; ++n) s00 = cadd(s00, w00[n]);
    out[2048] = cscale(s00, 0.5f * step);
  }
}

// ---------------------------------------------------------------------------
// fft_kd body (one d): odd bins KdO[d][m] = FFT4096(Re(K[n]) e^{-i pi n/4096})[m].
__device__ void fft_kd_body(int d, cf* L, const float* __restrict__ KdE,
                            float* __restrict__ KdO){
  const int t = threadIdx.x;
  const cf* kdE = (const cf*)KdE + (size_t)d * 2049;
  cf* kdO = (cf*)KdO + (size_t)d * 2048;
  cf v[16];
  const float inv = 1.0f / 4096.0f;
  #pragma unroll
  for (int n1 = 0; n1 < 16; ++n1){
    int m = n1*256 + t;
    cf a = (m <= 2048) ? kdE[m] : cconj(kdE[4096 - m]);
    v[n1] = cscale(a, inv);
  }
  fft4096_reg<+1>(v, L);
  const int k1 = t >> 4, ka = t & 15;
  const int xb = (k1 ^ ka) + 16*ka;
  const int swt = t ^ k1;
  __syncthreads();
  #pragma unroll
  for (int kb = 0; kb < 16; ++kb){
    int g = k1 + 16*ka + 256*kb;
    float kr = v[RI(kb)].x;
    float sn, cs; __sincosf(-7.669903939428206e-4f * (float)g, &sn, &cs);
    L[xb + 256*kb] = mkcf(kr*cs, kr*sn);
  }
  __syncthreads();
  #pragma unroll
  for (int n1 = 0; n1 < 16; ++n1) v[n1] = L[swt + n1*256];
  fft4096_reg<-1>(v, L);
  #pragma unroll
  for (int kb = 0; kb < 8; ++kb)
    kdO[k1 + 16*ka + 256*kb] = v[RI(kb)];
}

// ---------------------------------------------------------------------------
// fused_mid: blocks [0,256) = fft_kd; blocks [256,8448) = u transpose.
__global__ __launch_bounds__(256)
void fused_mid(const float* __restrict__ KdE, float* __restrict__ KdO,
               const float* __restrict__ u, float* __restrict__ ut){
  __shared__ cf L[4096];
  const int bid = blockIdx.x;
  if (bid < 256){
    fft_kd_body(bid, L, KdE, KdO);
    return;
  }
  float (*tile)[33] = (float(*)[33])L;
  const int m  = bid - 256;
  const int l0 = (m & 127) * 32;
  const int d0 = ((m >> 7) & 7) * 32;
  const int b  = m >> 10;
  const int tx = threadIdx.x & 31;
  const int ty = threadIdx.x >> 5;
  const float* ub = u + (size_t)b * 4096 * 256;
  #pragma unroll
  for (int it = 0; it < 4; ++it){
    int l = l0 + ty + it*8;
    tile[tx][ty + it*8] = ub[(size_t)l*256 + d0 + tx];
  }
  __syncthreads();
  float* utb = ut + (size_t)b * 256 * 4096;
  #pragma unroll
  for (int it = 0; it < 4; ++it){
    int dd = d0 + ty + it*8;
    utb[(size_t)dd*4096 + l0 + tx] = tile[ty + it*8][tx];
  }
}

// ---------------------------------------------------------------------------
// Fast exact-GELU: Phi via A&S 7.1.26 erfc (|err| < 1.5e-7).
__device__ __forceinline__ float gelu_exact(float x){
  float z = fabsf(x) * 0.70710678118654752f;
  float tt = __builtin_amdgcn_rcpf(fmaf(0.3275911f, z, 1.0f));
  float poly = fmaf(fmaf(fmaf(fmaf(1.061405429f, tt, -1.453152027f), tt,
                    1.421413741f), tt, -0.284496736f), tt, 0.254829592f) * tt;
  float ec = poly * __expf(-z*z);
  float phi = (x >= 0.f) ? fmaf(-0.5f, ec, 1.0f) : 0.5f * ec;
  return x * phi;
}

// ---------------------------------------------------------------------------
// Kernel 3: per-(b,d) non-circular conv via packed real-FFT; Kd PREFETCHED
// into registers before the forward FFT (latency hidden under ~1500 VALU);
// collapsed pointwise; fuses skip + GELU -> bf16 overlay.
__global__ __launch_bounds__(256, 5)
void s4_conv(float* __restrict__ ut, const float* __restrict__ KdE,
             const float* __restrict__ KdO, const float* __restrict__ Dsk){
  __shared__ cf L[4096];
  const int row = blockIdx.x;           // b*256 + d
  const int d   = row & 255;
  const int t   = threadIdx.x;
  cf* rp = (cf*)(ut + (size_t)row * 4096);
  const float dskd = Dsk[d];

  const cf* kdE = (const cf*)KdE + (size_t)d * 2049;
  const cf* kdO = (const cf*)KdO + (size_t)d * 2048;

  cf v[16], uin[8], kkv[8], kjv[8];
  #pragma unroll
  for (int n1 = 0; n1 < 8; ++n1){ uin[n1] = rp[n1*256 + t]; v[n1] = uin[n1]; }
  #pragma unroll
  for (int n1 = 8; n1 < 16; ++n1) v[n1] = mkcf(0.f, 0.f);
  // prefetch the divergent Kd loads (k=0 lane gets kdE[0], kdE[2048] - correct)
  #pragma unroll
  for (int m = 0; m < 8; ++m){
    int k = t + m*256;
    int h = k >> 1;
    if (k & 1){ kkv[m] = kdO[h]; kjv[m] = kdO[2047 - h]; }
    else      { kkv[m] = kdE[h]; kjv[m] = kdE[2048 - h]; }
  }

  fft4096_reg<-1, true>(v, L);          // Z (half-zero input)
  const int k1 = t >> 4, ka = t & 15;
  const int xb  = (k1 ^ ka) + 16*ka;
  const int swt = t ^ k1;
  const int t2  = 256 - t;
  const int swt2 = t2 ^ ((t2 >> 4) & 15);
  __syncthreads();
  #pragma unroll
  for (int kb = 0; kb < 16; ++kb)
    L[xb + 256*kb] = v[RI(kb)];
  __syncthreads();

  #pragma unroll
  for (int m = 0; m < 8; ++m){
    int k = t + m*256;                  // 0..2047
    if (k == 0){
      cf z0 = L[0];
      float U0 = z0.x + z0.y, UN = z0.x - z0.y;
      cf P0 = cscale(kkv[0], U0);       // kdE[0]
      cf PN = cscale(kjv[0], UN);       // kdE[2048]
      cf cPN = cconj(PN);
      cf Ep = cscale(cadd(P0, cPN), 0.5f);
      cf Op = cscale(csub(P0, cPN), 0.5f);
      L[0] = mkcf(Ep.x - Op.y, Ep.y + Op.x);
      cf P = cmul(cconj(L[2048]), kdE[1024]);   // uniform -> s_load
      L[2048] = cconj(P);
    } else {
      cf zk = L[swt + m*256];
      cf zj = L[(15 - m)*256 + swt2];
      cf kk = kkv[m], kj = kjv[m];
      float sn, cs; __sincosf(7.669903939428206e-4f * (float)k, &sn, &cs); // pi*k/4096
      cf KS = mkcf(0.5f*(kk.x + kj.x), 0.5f*(kk.y - kj.y));
      cf KD = mkcf(0.5f*(kk.x - kj.x), 0.5f*(kk.y + kj.y));
      cf KA  = KS - KD * sn;
      cf KAp = KS + KD * sn;
      cf KB  = mkcf(-cs * KD.y, cs * KD.x);   // i*c*KD
      cf Ak, Aj;
      // A[k] = KA*zk + KB*conj(zj)
      Ak.x = fmaf(KA.x, zk.x, fmaf(-KA.y, zk.y, fmaf(KB.x, zj.x,  KB.y*zj.y)));
      Ak.y = fmaf(KA.x, zk.y, fmaf( KA.y, zk.x, fmaf(KB.y, zj.x, -KB.x*zj.y)));
      // A[4096-k] = conj(KAp)*zj - conj(KB*zk)
      Aj.x = fmaf( KAp.x, zj.x, fmaf(KAp.y, zj.y, fmaf(-KB.x, zk.x, KB.y*zk.y)));
      Aj.y = fmaf(-KAp.y, zj.x, fmaf(KAp.x, zj.y, fmaf( KB.x, zk.y, KB.y*zk.x)));
      L[swt + m*256] = Ak;
      L[(15 - m)*256 + swt2] = Aj;
    }
  }
  __syncthreads();

  #pragma unroll
  for (int n1 = 0; n1 < 16; ++n1) v[n1] = L[swt + n1*256];
  fft4096_reg<+1>(v, L);

  __syncthreads();
  #pragma unroll
  for (int kb = 0; kb < 8; ++kb)
    L[xb + 256*kb] = v[RI(kb)];
  __syncthreads();
  const float inv = 1.0f / 4096.0f;
  unsigned* og = (unsigned*)rp;         // bf16 overlay (2 tokens / dword)
  #pragma unroll
  for (int n1 = 0; n1 < 8; ++n1){
    cf cv = L[swt + n1*256];
    float x0 = fmaf(dskd, uin[n1].x, cv.x * inv);
    float x1 = fmaf(dskd, uin[n1].y, cv.y * inv);
    unsigned b0 = (unsigned)(unsigned short)f2bf(gelu_exact(x0));
    unsigned b1 = (unsigned)(unsigned short)f2bf(gelu_exact(x1));
    og[n1*256 + t] = b0 | (b1 << 16);
  }
}

// ---------------------------------------------------------------------------
// Kernel 5: X = Z @ W^T + b + u ; LayerNorm -> out.  32 tokens/block (grid
// 1024).  acc C-INITIALIZED with (bias + u); Wbf fragment-major; St
// double-buffered (one barrier per k-chunk).
__global__ __launch_bounds__(256)
void mfma_gemm_ln(const float* __restrict__ utg, const short* __restrict__ Wbf,
                  const float* __restrict__ bias, const float* __restrict__ u,
                  const float* __restrict__ gamma, const float* __restrict__ beta,
                  float* __restrict__ out){
  __shared__ short St[2][64][32];     // double-buffered k-chunk stage
  __shared__ float prm[2][256];       // gamma / beta
  __shared__ float2 red[2][2][16];    // [tok-half][feat-half][lm]
  const int w    = threadIdx.x >> 6;
  const int l    = threadIdx.x & 63;
  const int lm   = l & 15;
  const int lk   = l >> 4;
  const int tokB = blockIdx.x * 32;   // never straddles batch (32 | 4096)
  const int b    = tokB >> 12;
  const int l0   = tokB & 4095;

  prm[0][threadIdx.x] = gamma[threadIdx.x];
  prm[1][threadIdx.x] = beta[threadIdx.x];

  const int srow = l >> 2;            // k-row within warp's 16
  const int tg   = l & 3;             // token-group of 8
  const char* ubase = (const char*)utg + (size_t)(b * 256) * 16384;
  bf16x8 pre[4];
  #pragma unroll
  for (int c = 0; c < 4; ++c){
    int r = c*64 + w*16 + srow;
    pre[c] = *(const bf16x8*)((const unsigned short*)(ubase + (size_t)r * 16384) + l0 + tg*8);
  }

  const int th = (w & 1) * 16;        // token half
  const int fh2 = w >> 1;
  const int fh = fh2 * 128;           // feature half
  const int tt = tokB + th + lm;      // this lane's token
  const float* ur = u + (size_t)tt * 256 + fh;
  const float* br = bias + fh;
  f32x4 acc[8];
  #pragma unroll
  for (int nt = 0; nt < 8; ++nt){
    const float4 uv = *(const float4*)(ur + nt*16 + lk*4);
    const float4 bv = *(const float4*)(br + nt*16 + lk*4);
    acc[nt] = (f32x4){uv.x + bv.x, uv.y + bv.y, uv.z + bv.z, uv.w + bv.w};
  }

  const int tg_tok = (th + lm) >> 3;
  const int tlo    = lm & 7;

  #pragma unroll
  for (int c = 0; c < 4; ++c){
    const int buf = c & 1;
    {
      int r  = w*16 + srow;
      int sl = (tg ^ ((r >> 3) & 3)) * 8;
      *(bf16x8*)&St[buf][r][sl] = pre[c];
    }
    __syncthreads();                  // one barrier per chunk (dbuf)
    #pragma unroll
    for (int s2 = 0; s2 < 2; ++s2){
      const int ks  = c*2 + s2;
      const int idx = ((tg_tok ^ lk) << 3) | tlo;
      bf16x8 zf;
      #pragma unroll
      for (int j = 0; j < 8; ++j)
        zf[j] = St[buf][s2*32 + lk*8 + j][idx];
      const short* wbase = Wbf + (size_t)(ks*2 + fh2)*4096 + lk*128 + lm*8;
      #pragma unroll
      for (int nt = 0; nt < 8; ++nt){
        const bf16x8* ap = (const bf16x8*)(wbase + nt*512);
        acc[nt] = __builtin_amdgcn_mfma_f32_16x16x32_bf16(*ap, zf, acc[nt], 0, 0, 0);
      }
    }
  }

  float s = 0.f, s2 = 0.f;
  #pragma unroll
  for (int nt = 0; nt < 8; ++nt){
    s += acc[nt][0] + acc[nt][1] + acc[nt][2] + acc[nt][3];
    s2 = fmaf(acc[nt][0], acc[nt][0], s2);
    s2 = fmaf(acc[nt][1], acc[nt][1], s2);
    s2 = fmaf(acc[nt][2], acc[nt][2], s2);
    s2 = fmaf(acc[nt][3], acc[nt][3], s2);
  }
  s  += __shfl_xor(s,  16); s  += __shfl_xor(s,  32);
  s2 += __shfl_xor(s2, 16); s2 += __shfl_xor(s2, 32);
  __syncthreads();
  if (lk == 0) red[w & 1][fh2][lm] = make_float2(s, s2);
  __syncthreads();
  const float2 pj = red[w & 1][fh2 ^ 1][lm];
  const float st = s + pj.x, s2t = s2 + pj.y;
  const float mu = st * (1.0f/256.0f);
  const float rs = rsqrtf(s2t * (1.0f/256.0f) - mu*mu + 1e-5f);
  float* orow = out + (size_t)tt * 256 + fh;
  #pragma unroll
  for (int nt = 0; nt < 8; ++nt){
    const int f0 = fh + nt*16 + lk*4;
    const float4 gv = *(const float4*)&prm[0][f0];
    const float4 ev = *(const float4*)&prm[1][f0];
    float4 o;
    o.x = (acc[nt][0] - mu) * rs * gv.x + ev.x;
    o.y = (acc[nt][1] - mu) * rs * gv.y + ev.y;
    o.z = (acc[nt][2] - mu) * rs * gv.z + ev.z;
    o.w = (acc[nt][3] - mu) * rs * gv.w + ev.w;
    *(float4*)(orow + nt*16 + lk*4) = o;
  }
}

// ---------------------------------------------------------------------------
extern "C" void kernel_launch(void* const* d_in, const int* in_sizes, int n_in,
                              void* d_out, int out_size, void* d_ws, size_t ws_size,
                              hipStream_t stream){
  (void)in_sizes; (void)n_in; (void)out_size; (void)ws_size;
  const float* u        = (const float*)d_in[0];
  const float* B_ri     = (const float*)d_in[1];
  const float* Ct_ri    = (const float*)d_in[2];
  const float* lam_ri   = (const float*)d_in[3];
  const float* p_ri     = (const float*)d_in[4];
  const float* q_ri     = (const float*)d_in[5];
  const float* log_step = (const float*)d_in[6];
  const float* D_skip   = (const float*)d_in[7];
  const float* W        = (const float*)d_in[8];
  const float* bias     = (const float*)d_in[9];
  const float* gamma    = (const float*)d_in[10];
  const float* beta     = (const float*)d_in[11];
  float* out = (float*)d_out;

  // Workspace: KdE 4,196,352 | KdO 4,194,304 | Wbf 131,072 | ut 33,554,432
  char* ws = (char*)d_ws;
  float* KdE = (float*)(ws);
  float* KdO = (float*)(ws + 4196352);
  short* Wbf = (short*)(ws + 4196352 + 4194304);
  float* ut  = (float*)(ws + 4196352 + 4194304 + 131072);

  fused_head  <<<2112, 256, 0, stream>>>(B_ri, Ct_ri, lam_ri, p_ri, q_ri,
                                         log_step, KdE, W, Wbf);
  fused_mid   <<<8448, 256, 0, stream>>>(KdE, KdO, u, ut);
  s4_conv     <<<2048, 256, 0, stream>>>(ut, KdE, KdO, D_skip);
  mfma_gemm_ln<<<1024, 256, 0, stream>>>(ut, Wbf, bias, u, gamma, beta, out);
}

// Round 16
// 102.195 us; speedup vs baseline: 1.1795x; 1.1795x over previous
//
#include <hip/hip_runtime.h>
#include <math.h>

// S4 block: fused-head (Cauchy + W-convert), fused-mid (Kd FFT + u-transpose),
// s4_conv (reg FFTs + collapsed pointwise + skip+GELU -> bf16 overlay),
// MFMA GEMM+LN (double-buffered staging).  B=8, L=4096, D=256, N=64.

typedef __attribute__((ext_vector_type(2))) float cf;
typedef __attribute__((ext_vector_type(8))) short bf16x8;
typedef __attribute__((ext_vector_type(4))) float f32x4;

__device__ __forceinline__ cf mkcf(float x, float y){ cf r; r.x = x; r.y = y; return r; }

__device__ __forceinline__ cf cadd(cf a, cf b){ return a + b; }       // v_pk_add_f32
__device__ __forceinline__ cf csub(cf a, cf b){ return a - b; }
__device__ __forceinline__ cf cscale(cf a, float s){ return a * s; }  // v_pk_mul_f32
__device__ __forceinline__ cf cconj(cf a){ return mkcf(a.x, -a.y); }
__device__ __forceinline__ cf cmul(cf a, cf b){                       // scalar 4-fma
  return mkcf(fmaf(a.x, b.x, -a.y*b.y), fmaf(a.x, b.y, a.y*b.x));
}
// acc += a*b, fused (4 fma)
__device__ __forceinline__ void cmacc(cf& acc, cf a, cf b){
  acc.x = fmaf(a.x, b.x, fmaf(-a.y, b.y, acc.x));
  acc.y = fmaf(a.x, b.y, fmaf( a.y, b.x, acc.y));
}

__device__ __forceinline__ short f2bf(float x){   // RNE float->bf16
  union { float f; unsigned u; } v; v.f = x;
  unsigned r = v.u + 0x7fffu + ((v.u >> 16) & 1u);
  return (short)(r >> 16);
}

__device__ __forceinline__ constexpr int RI(int k){ return ((k & 3) << 2) | (k >> 2); }

#define C8 0.92387953251f
#define S8 0.38268343236f
#define RH 0.70710678119f

template<int DIR>
__device__ __forceinline__ void r4(cf& a, cf& b, cf& c, cf& d){
  cf T0 = a + c, T1 = a - c;
  cf T2 = b + d, Bd = b - d;
  a = T0 + T2; c = T0 - T2;
  cf iBd = (DIR > 0) ? mkcf(-Bd.y, Bd.x) : mkcf(Bd.y, -Bd.x);   // ±i*Bd
  b = T1 + iBd; d = T1 - iBd;
}

// FFT16; if HZ, inputs v[8..15] are known zero (stage-1 r4s degenerate).
template<int DIR, bool HZ>
__device__ __forceinline__ void fft16(cf* v){
  if constexpr (HZ){
    #pragma unroll
    for (int i = 0; i < 4; ++i){
      cf a = v[i], b = v[i+4];
      cf ib = (DIR > 0) ? mkcf(-b.y, b.x) : mkcf(b.y, -b.x);
      v[i]    = a + b;
      v[i+8]  = a - b;
      v[i+4]  = a + ib;
      v[i+12] = a - ib;
    }
  } else {
    r4<DIR>(v[0], v[4], v[8],  v[12]);
    r4<DIR>(v[1], v[5], v[9],  v[13]);
    r4<DIR>(v[2], v[6], v[10], v[14]);
    r4<DIR>(v[3], v[7], v[11], v[15]);
  }
  constexpr float D = (float)DIR;
  const cf w1 = mkcf(C8,  D*S8);
  const cf w2 = mkcf(RH,  D*RH);
  const cf w3 = mkcf(S8,  D*C8);
  const cf w6 = mkcf(-RH, D*RH);
  const cf w9 = mkcf(-C8, -D*S8);
  v[5]  = cmul(v[5],  w1);
  v[6]  = cmul(v[6],  w2);
  v[7]  = cmul(v[7],  w3);
  v[9]  = cmul(v[9],  w2);
  v[10] = (DIR > 0) ? mkcf(-v[10].y, v[10].x) : mkcf(v[10].y, -v[10].x);
  v[11] = cmul(v[11], w6);
  v[13] = cmul(v[13], w3);
  v[14] = cmul(v[14], w6);
  v[15] = cmul(v[15], w9);
  r4<DIR>(v[0],  v[1],  v[2],  v[3]);
  r4<DIR>(v[4],  v[5],  v[6],  v[7]);
  r4<DIR>(v[8],  v[9],  v[10], v[11]);
  r4<DIR>(v[12], v[13], v[14], v[15]);
}

// 4096-pt FFT, four-step 16x(16x16).  Entry: v[n1] = x[n1*256 + t].
// Exit: V[k1+16*ka+256*kb] = v[RI(kb)], k1 = t>>4, ka = t&15.
template<int DIR, bool HZ = false>
__device__ void fft4096_reg(cf* v, cf* lds){
  const int t = threadIdx.x;
  const int k1 = t >> 4, m2 = t & 15;
  const int swt = t ^ k1;
  constexpr float D = (float)DIR;
  fft16<DIR, HZ>(v);
  float sn, cs;
  __sincosf(D * 1.5339807878856412e-3f * (float)t, &sn, &cs);   // 2pi/4096
  __syncthreads();
  {
    cf* p = lds + swt;
    cf w1 = mkcf(cs, sn);
    p[0]    = v[0];
    p[256]  = cmul(v[RI(1)],  w1);
    cf w2 = cmul(w1, w1);
    p[512]  = cmul(v[RI(2)],  w2);
    cf w3 = cmul(w2, w1);
    p[768]  = cmul(v[RI(3)],  w3);
    cf w4 = cmul(w2, w2);
    p[1024] = cmul(v[RI(4)],  w4);
    cf w5 = cmul(w4, w1);
    p[1280] = cmul(v[RI(5)],  w5);
    cf w6 = cmul(w4, w2);
    p[1536] = cmul(v[RI(6)],  w6);
    cf w7 = cmul(w4, w3);
    p[1792] = cmul(v[RI(7)],  w7);
    cf w8 = cmul(w4, w4);
    p[2048] = cmul(v[RI(8)],  w8);
    p[2304] = cmul(v[RI(9)],  cmul(w8, w1));
    p[2560] = cmul(v[RI(10)], cmul(w8, w2));
    p[2816] = cmul(v[RI(11)], cmul(w8, w3));
    p[3072] = cmul(v[RI(12)], cmul(w8, w4));
    p[3328] = cmul(v[RI(13)], cmul(w8, w5));
    p[3584] = cmul(v[RI(14)], cmul(w8, w6));
    p[3840] = cmul(v[RI(15)], cmul(w8, w7));
  }
  __syncthreads();
  {
    cf* p = lds + k1*256;
    #pragma unroll
    for (int m1 = 0; m1 < 16; ++m1) v[m1] = p[m1*16 + (m2 ^ m1)];
  }
  fft16<DIR, false>(v);
  __sincosf(D * 2.45436926061703e-2f * (float)m2, &sn, &cs);    // 2pi/256
  __syncthreads();
  {
    cf* p = lds + k1*256;
    cf w1 = mkcf(cs, sn);
    p[m2]              = v[0];
    p[16  + (m2^1)]    = cmul(v[RI(1)],  w1);
    cf w2 = cmul(w1, w1);
    p[32  + (m2^2)]    = cmul(v[RI(2)],  w2);
    cf w3 = cmul(w2, w1);
    p[48  + (m2^3)]    = cmul(v[RI(3)],  w3);
    cf w4 = cmul(w2, w2);
    p[64  + (m2^4)]    = cmul(v[RI(4)],  w4);
    cf w5 = cmul(w4, w1);
    p[80  + (m2^5)]    = cmul(v[RI(5)],  w5);
    cf w6 = cmul(w4, w2);
    p[96  + (m2^6)]    = cmul(v[RI(6)],  w6);
    cf w7 = cmul(w4, w3);
    p[112 + (m2^7)]    = cmul(v[RI(7)],  w7);
    cf w8 = cmul(w4, w4);
    p[128 + (m2^8)]    = cmul(v[RI(8)],  w8);
    p[144 + (m2^9)]    = cmul(v[RI(9)],  cmul(w8, w1));
    p[160 + (m2^10)]   = cmul(v[RI(10)], cmul(w8, w2));
    p[176 + (m2^11)]   = cmul(v[RI(11)], cmul(w8, w3));
    p[192 + (m2^12)]   = cmul(v[RI(12)], cmul(w8, w4));
    p[208 + (m2^13)]   = cmul(v[RI(13)], cmul(w8, w5));
    p[224 + (m2^14)]   = cmul(v[RI(14)], cmul(w8, w6));
    p[240 + (m2^15)]   = cmul(v[RI(15)], cmul(w8, w7));
  }
  __syncthreads();
  {
    const int ka = m2;
    cf* p = lds + k1*256 + ka*16;
    #pragma unroll
    for (int m2b = 0; m2b < 16; ++m2b) v[m2b] = p[m2b ^ ka];
  }
  fft16<DIR, false>(v);
}

// ---------------------------------------------------------------------------
// fused_head: blocks [0,2048) = Cauchy (Hermitian half -> KdE even bins);
// blocks [2048,2112) = W f32->bf16 fragment-major.
__global__ __launch_bounds__(256)
void fused_head(const float* __restrict__ B_ri, const float* __restrict__ Ct_ri,
                const float* __restrict__ lam_ri, const float* __restrict__ p_ri,
                const float* __restrict__ q_ri, const float* __restrict__ log_step,
                float* __restrict__ KdE,
                const float* __restrict__ W, short* __restrict__ Wbf){
  __shared__ cf w00[64], w01[64], w10[64], w11[64], lamS[64];
  const int bid = blockIdx.x;
  const int tid = threadIdx.x;

  if (bid >= 2048){
    int t  = (bid - 2048) * 256 + tid;          // 16384 threads
    int o4 = t * 4;
    int j   = o4 & 7;
    int lm  = (o4 >> 3)  & 15;
    int lk  = (o4 >> 7)  & 3;
    int nt  = (o4 >> 9)  & 7;
    int fh2 = (o4 >> 12) & 1;
    int ks  = o4 >> 13;
    int f = fh2*128 + nt*16 + lm;
    int k = ks*32 + lk*8 + j;
    float4 wv = *(const float4*)(W + (size_t)f*256 + k);
    short4 o;
    o.x = f2bf(wv.x); o.y = f2bf(wv.y); o.z = f2bf(wv.z); o.w = f2bf(wv.w);
    *(short4*)(Wbf + o4) = o;
    return;
  }

  const int d     = bid >> 3;
  const int chunk = bid & 7;
  const float step = expf(log_step[d]);

  if (tid < 64){
    int n = tid;
    cf Bv = mkcf(B_ri[(d*64+n)*2],  B_ri[(d*64+n)*2+1]);
    cf Cv = mkcf(Ct_ri[(d*64+n)*2], Ct_ri[(d*64+n)*2+1]);
    cf pv = mkcf(p_ri[n*2], p_ri[n*2+1]);
    cf qv = mkcf(q_ri[n*2], q_ri[n*2+1]);
    lamS[n] = mkcf(lam_ri[n*2], lam_ri[n*2+1]);
    cf Cc = cconj(Cv), qc = cconj(qv);
    w00[n] = cmul(Cc, Bv);
    w01[n] = cmul(Cc, pv);
    w10[n] = cmul(qc, Bv);
    w11[n] = cmul(qc, pv);
  }
  __syncthreads();

  cf* out = (cf*)KdE + (size_t)d * 2049;
  const int l = chunk * 256 + tid;               // 0..2047
  {
    float th = -(6.28318530717958647692f * (float)l) * (1.0f/4096.0f);
    float sn, cs; __sincosf(th, &sn, &cs);
    cf opw = mkcf(1.0f + cs,  sn);               // 1 + omega
    cf omw = mkcf(1.0f - cs, -sn);               // 1 - omega
    float idn = __builtin_amdgcn_rcpf(fmaf(opw.x, opw.x, opw.y*opw.y));
    cf ratio = mkcf((omw.x*opw.x + omw.y*opw.y)*idn,
                    (omw.y*opw.x - omw.x*opw.y)*idn);
    cf g  = cscale(ratio, 2.0f / step);
    cf cc = mkcf(2.0f*opw.x*idn, -2.0f*opw.y*idn);   // 2/(1+omega)
    cf k00 = mkcf(0,0), k01 = mkcf(0,0), k10 = mkcf(0,0), k11 = mkcf(0,0);
    #pragma unroll 4
    for (int n = 0; n < 64; ++n){
      cf den = g - lamS[n];
      float is = __builtin_amdgcn_rcpf(fmaf(den.x, den.x, den.y*den.y));
      cf r = mkcf(den.x*is, -den.y*is);              // 1/(g - lam)
      cmacc(k00, w00[n], r);
      cmacc(k01, w01[n], r);
      cmacc(k10, w10[n], r);
      cmacc(k11, w11[n], r);
    }
    cf onep = mkcf(1.0f + k11.x, k11.y);
    float ii = __builtin_amdgcn_rcpf(fmaf(onep.x, onep.x, onep.y*onep.y));
    cf inv1p = mkcf(onep.x*ii, -onep.y*ii);
    cf corr = cmul(k01, cmul(k10, inv1p));
    out[l] = cmul(cc, csub(k00, corr));
  }
  if (chunk == 7 && tid == 255){
    cf s00 = mkcf(0.f, 0.f);
    for (int n = 0; n < 64; ++n) s00 = cadd(s00, w00[n]);
    out[2048] = cscale(s00, 0.5f * step);
  }
}

// ---------------------------------------------------------------------------
// fft_kd body (one d): odd bins KdO[d][m] = FFT4096(Re(K[n]) e^{-i pi n/4096})[m].
__device__ void fft_kd_body(int d, cf* L, const float* __restrict__ KdE,
                            float* __restrict__ KdO){
  const int t = threadIdx.x;
  const cf* kdE = (const cf*)KdE + (size_t)d * 2049;
  cf* kdO = (cf*)KdO + (size_t)d * 2048;
  cf v[16];
  const float inv = 1.0f / 4096.0f;
  #pragma unroll
  for (int n1 = 0; n1 < 16; ++n1){
    int m = n1*256 + t;
    cf a = (m <= 2048) ? kdE[m] : cconj(kdE[4096 - m]);
    v[n1] = cscale(a, inv);
  }
  fft4096_reg<+1>(v, L);
  const int k1 = t >> 4, ka = t & 15;
  const int xb = (k1 ^ ka) + 16*ka;
  const int swt = t ^ k1;
  __syncthreads();
  #pragma unroll
  for (int kb = 0; kb < 16; ++kb){
    int g = k1 + 16*ka + 256*kb;
    float kr = v[RI(kb)].x;
    float sn, cs; __sincosf(-7.669903939428206e-4f * (float)g, &sn, &cs);
    L[xb + 256*kb] = mkcf(kr*cs, kr*sn);
  }
  __syncthreads();
  #pragma unroll
  for (int n1 = 0; n1 < 16; ++n1) v[n1] = L[swt + n1*256];
  fft4096_reg<-1>(v, L);
  #pragma unroll
  for (int kb = 0; kb < 8; ++kb)
    kdO[k1 + 16*ka + 256*kb] = v[RI(kb)];
}

// ---------------------------------------------------------------------------
// fused_mid: blocks [0,256) = fft_kd; blocks [256,8448) = u transpose.
__global__ __launch_bounds__(256)
void fused_mid(const float* __restrict__ KdE, float* __restrict__ KdO,
               const float* __restrict__ u, float* __restrict__ ut){
  __shared__ cf L[4096];
  const int bid = blockIdx.x;
  if (bid < 256){
    fft_kd_body(bid, L, KdE, KdO);
    return;
  }
  float (*tile)[33] = (float(*)[33])L;
  const int m  = bid - 256;
  const int l0 = (m & 127) * 32;
  const int d0 = ((m >> 7) & 7) * 32;
  const int b  = m >> 10;
  const int tx = threadIdx.x & 31;
  const int ty = threadIdx.x >> 5;
  const float* ub = u + (size_t)b * 4096 * 256;
  #pragma unroll
  for (int it = 0; it < 4; ++it){
    int l = l0 + ty + it*8;
    tile[tx][ty + it*8] = ub[(size_t)l*256 + d0 + tx];
  }
  __syncthreads();
  float* utb = ut + (size_t)b * 256 * 4096;
  #pragma unroll
  for (int it = 0; it < 4; ++it){
    int dd = d0 + ty + it*8;
    utb[(size_t)dd*4096 + l0 + tx] = tile[ty + it*8][tx];
  }
}

// ---------------------------------------------------------------------------
// Fast exact-GELU: Phi via A&S 7.1.26 erfc (|err| < 1.5e-7).
__device__ __forceinline__ float gelu_exact(float x){
  float z = fabsf(x) * 0.70710678118654752f;
  float tt = __builtin_amdgcn_rcpf(fmaf(0.3275911f, z, 1.0f));
  float poly = fmaf(fmaf(fmaf(fmaf(1.061405429f, tt, -1.453152027f), tt,
                    1.421413741f), tt, -0.284496736f), tt, 0.254829592f) * tt;
  float ec = poly * __expf(-z*z);
  float phi = (x >= 0.f) ? fmaf(-0.5f, ec, 1.0f) : 0.5f * ec;
  return x * phi;
}

// ---------------------------------------------------------------------------
// Kernel 3: per-(b,d) non-circular conv via packed real-FFT; collapsed
// pointwise A[k] = KA*zk + KB*conj(zj); fuses skip + GELU -> bf16 overlay.
// Kd loads stay in-loop (register prefetch spilled to scratch, round-15).
__global__ __launch_bounds__(256)
void s4_conv(float* __restrict__ ut, const float* __restrict__ KdE,
             const float* __restrict__ KdO, const float* __restrict__ Dsk){
  __shared__ cf L[4096];
  const int row = blockIdx.x;           // b*256 + d
  const int d   = row & 255;
  const int t   = threadIdx.x;
  cf* rp = (cf*)(ut + (size_t)row * 4096);
  const float dskd = Dsk[d];

  cf v[16], uin[8];
  #pragma unroll
  for (int n1 = 0; n1 < 8; ++n1){ uin[n1] = rp[n1*256 + t]; v[n1] = uin[n1]; }
  #pragma unroll
  for (int n1 = 8; n1 < 16; ++n1) v[n1] = mkcf(0.f, 0.f);

  fft4096_reg<-1, true>(v, L);          // Z (half-zero input)
  const int k1 = t >> 4, ka = t & 15;
  const int xb  = (k1 ^ ka) + 16*ka;
  const int swt = t ^ k1;
  const int t2  = 256 - t;
  const int swt2 = t2 ^ ((t2 >> 4) & 15);
  __syncthreads();
  #pragma unroll
  for (int kb = 0; kb < 16; ++kb)
    L[xb + 256*kb] = v[RI(kb)];
  __syncthreads();

  const cf* kdE = (const cf*)KdE + (size_t)d * 2049;
  const cf* kdO = (const cf*)KdO + (size_t)d * 2048;
  #pragma unroll
  for (int m = 0; m < 8; ++m){
    int k = t + m*256;                  // 0..2047
    if (k == 0){
      cf z0 = L[0];
      float U0 = z0.x + z0.y, UN = z0.x - z0.y;
      cf P0 = cscale(kdE[0], U0);
      cf PN = cscale(kdE[2048], UN);
      cf cPN = cconj(PN);
      cf Ep = cscale(cadd(P0, cPN), 0.5f);
      cf Op = cscale(csub(P0, cPN), 0.5f);
      L[0] = mkcf(Ep.x - Op.y, Ep.y + Op.x);
      cf P = cmul(cconj(L[2048]), kdE[1024]);
      L[2048] = cconj(P);
    } else {
      cf zk = L[swt + m*256];
      cf zj = L[(15 - m)*256 + swt2];
      int h = k >> 1;
      cf kk, kj;
      if (k & 1){ kk = kdO[h]; kj = kdO[2047 - h]; }
      else      { kk = kdE[h]; kj = kdE[2048 - h]; }
      float sn, cs; __sincosf(7.669903939428206e-4f * (float)k, &sn, &cs); // pi*k/4096
      cf KS = mkcf(0.5f*(kk.x + kj.x), 0.5f*(kk.y - kj.y));
      cf KD = mkcf(0.5f*(kk.x - kj.x), 0.5f*(kk.y + kj.y));
      cf KA  = KS - KD * sn;
      cf KAp = KS + KD * sn;
      cf KB  = mkcf(-cs * KD.y, cs * KD.x);   // i*c*KD
      cf Ak, Aj;
      // A[k] = KA*zk + KB*conj(zj)
      Ak.x = fmaf(KA.x, zk.x, fmaf(-KA.y, zk.y, fmaf(KB.x, zj.x,  KB.y*zj.y)));
      Ak.y = fmaf(KA.x, zk.y, fmaf( KA.y, zk.x, fmaf(KB.y, zj.x, -KB.x*zj.y)));
      // A[4096-k] = conj(KAp)*zj - conj(KB*zk)
      Aj.x = fmaf( KAp.x, zj.x, fmaf(KAp.y, zj.y, fmaf(-KB.x, zk.x, KB.y*zk.y)));
      Aj.y = fmaf(-KAp.y, zj.x, fmaf(KAp.x, zj.y, fmaf( KB.x, zk.y, KB.y*zk.x)));
      L[swt + m*256] = Ak;
      L[(15 - m)*256 + swt2] = Aj;
    }
  }
  __syncthreads();

  #pragma unroll
  for (int n1 = 0; n1 < 16; ++n1) v[n1] = L[swt + n1*256];
  fft4096_reg<+1>(v, L);

  __syncthreads();
  #pragma unroll
  for (int kb = 0; kb < 8; ++kb)
    L[xb + 256*kb] = v[RI(kb)];
  __syncthreads();
  const float inv = 1.0f / 4096.0f;
  unsigned* og = (unsigned*)rp;         // bf16 overlay (2 tokens / dword)
  #pragma unroll
  for (int n1 = 0; n1 < 8; ++n1){
    cf cv = L[swt + n1*256];
    float x0 = fmaf(dskd, uin[n1].x, cv.x * inv);
    float x1 = fmaf(dskd, uin[n1].y, cv.y * inv);
    unsigned b0 = (unsigned)(unsigned short)f2bf(gelu_exact(x0));
    unsigned b1 = (unsigned)(unsigned short)f2bf(gelu_exact(x1));
    og[n1*256 + t] = b0 | (b1 << 16);
  }
}

// ---------------------------------------------------------------------------
// Kernel 5: X = Z @ W^T + b + u ; LayerNorm -> out.  32 tokens/block (grid
// 1024).  acc C-INITIALIZED with (bias + u); Wbf fragment-major; St
// double-buffered (one barrier per k-chunk).
__global__ __launch_bounds__(256)
void mfma_gemm_ln(const float* __restrict__ utg, const short* __restrict__ Wbf,
                  const float* __restrict__ bias, const float* __restrict__ u,
                  const float* __restrict__ gamma, const float* __restrict__ beta,
                  float* __restrict__ out){
  __shared__ short St[2][64][32];     // double-buffered k-chunk stage
  __shared__ float prm[2][256];       // gamma / beta
  __shared__ float2 red[2][2][16];    // [tok-half][feat-half][lm]
  const int w    = threadIdx.x >> 6;
  const int l    = threadIdx.x & 63;
  const int lm   = l & 15;
  const int lk   = l >> 4;
  const int tokB = blockIdx.x * 32;   // never straddles batch (32 | 4096)
  const int b    = tokB >> 12;
  const int l0   = tokB & 4095;

  prm[0][threadIdx.x] = gamma[threadIdx.x];
  prm[1][threadIdx.x] = beta[threadIdx.x];

  const int srow = l >> 2;            // k-row within warp's 16
  const int tg   = l & 3;             // token-group of 8
  const char* ubase = (const char*)utg + (size_t)(b * 256) * 16384;
  bf16x8 pre[4];
  #pragma unroll
  for (int c = 0; c < 4; ++c){
    int r = c*64 + w*16 + srow;
    pre[c] = *(const bf16x8*)((const unsigned short*)(ubase + (size_t)r * 16384) + l0 + tg*8);
  }

  const int th = (w & 1) * 16;        // token half
  const int fh2 = w >> 1;
  const int fh = fh2 * 128;           // feature half
  const int tt = tokB + th + lm;      // this lane's token
  const float* ur = u + (size_t)tt * 256 + fh;
  const float* br = bias + fh;
  f32x4 acc[8];
  #pragma unroll
  for (int nt = 0; nt < 8; ++nt){
    const float4 uv = *(const float4*)(ur + nt*16 + lk*4);
    const float4 bv = *(const float4*)(br + nt*16 + lk*4);
    acc[nt] = (f32x4){uv.x + bv.x, uv.y + bv.y, uv.z + bv.z, uv.w + bv.w};
  }

  const int tg_tok = (th + lm) >> 3;
  const int tlo    = lm & 7;

  #pragma unroll
  for (int c = 0; c < 4; ++c){
    const int buf = c & 1;
    {
      int r  = w*16 + srow;
      int sl = (tg ^ ((r >> 3) & 3)) * 8;
      *(bf16x8*)&St[buf][r][sl] = pre[c];
    }
    __syncthreads();                  // one barrier per chunk (dbuf)
    #pragma unroll
    for (int s2 = 0; s2 < 2; ++s2){
      const int ks  = c*2 + s2;
      const int idx = ((tg_tok ^ lk) << 3) | tlo;
      bf16x8 zf;
      #pragma unroll
      for (int j = 0; j < 8; ++j)
        zf[j] = St[buf][s2*32 + lk*8 + j][idx];
      const short* wbase = Wbf + (size_t)(ks*2 + fh2)*4096 + lk*128 + lm*8;
      #pragma unroll
      for (int nt = 0; nt < 8; ++nt){
        const bf16x8* ap = (const bf16x8*)(wbase + nt*512);
        acc[nt] = __builtin_amdgcn_mfma_f32_16x16x32_bf16(*ap, zf, acc[nt], 0, 0, 0);
      }
    }
  }

  float s = 0.f, s2 = 0.f;
  #pragma unroll
  for (int nt = 0; nt < 8; ++nt){
    s += acc[nt][0] + acc[nt][1] + acc[nt][2] + acc[nt][3];
    s2 = fmaf(acc[nt][0], acc[nt][0], s2);
    s2 = fmaf(acc[nt][1], acc[nt][1], s2);
    s2 = fmaf(acc[nt][2], acc[nt][2], s2);
    s2 = fmaf(acc[nt][3], acc[nt][3], s2);
  }
  s  += __shfl_xor(s,  16); s  += __shfl_xor(s,  32);
  s2 += __shfl_xor(s2, 16); s2 += __shfl_xor(s2, 32);
  __syncthreads();
  if (lk == 0) red[w & 1][fh2][lm] = make_float2(s, s2);
  __syncthreads();
  const float2 pj = red[w & 1][fh2 ^ 1][lm];
  const float st = s + pj.x, s2t = s2 + pj.y;
  const float mu = st * (1.0f/256.0f);
  const float rs = rsqrtf(s2t * (1.0f/256.0f) - mu*mu + 1e-5f);
  float* orow = out + (size_t)tt * 256 + fh;
  #pragma unroll
  for (int nt = 0; nt < 8; ++nt){
    const int f0 = fh + nt*16 + lk*4;
    const float4 gv = *(const float4*)&prm[0][f0];
    const float4 ev = *(const float4*)&prm[1][f0];
    float4 o;
    o.x = (acc[nt][0] - mu) * rs * gv.x + ev.x;
    o.y = (acc[nt][1] - mu) * rs * gv.y + ev.y;
    o.z = (acc[nt][2] - mu) * rs * gv.z + ev.z;
    o.w = (acc[nt][3] - mu) * rs * gv.w + ev.w;
    *(float4*)(orow + nt*16 + lk*4) = o;
  }
}

// ---------------------------------------------------------------------------
extern "C" void kernel_launch(void* const* d_in, const int* in_sizes, int n_in,
                              void* d_out, int out_size, void* d_ws, size_t ws_size,
                              hipStream_t stream){
  (void)in_sizes; (void)n_in; (void)out_size; (void)ws_size;
  const float* u        = (const float*)d_in[0];
  const float* B_ri     = (const float*)d_in[1];
  const float* Ct_ri    = (const float*)d_in[2];
  const float* lam_ri   = (const float*)d_in[3];
  const float* p_ri     = (const float*)d_in[4];
  const float* q_ri     = (const float*)d_in[5];
  const float* log_step = (const float*)d_in[6];
  const float* D_skip   = (const float*)d_in[7];
  const float* W        = (const float*)d_in[8];
  const float* bias     = (const float*)d_in[9];
  const float* gamma    = (const float*)d_in[10];
  const float* beta     = (const float*)d_in[11];
  float* out = (float*)d_out;

  // Workspace: KdE 4,196,352 | KdO 4,194,304 | Wbf 131,072 | ut 33,554,432
  char* ws = (char*)d_ws;
  float* KdE = (float*)(ws);
  float* KdO = (float*)(ws + 4196352);
  short* Wbf = (short*)(ws + 4196352 + 4194304);
  float* ut  = (float*)(ws + 4196352 + 4194304 + 131072);

  fused_head  <<<2112, 256, 0, stream>>>(B_ri, Ct_ri, lam_ri, p_ri, q_ri,
                                         log_step, KdE, W, Wbf);
  fused_mid   <<<8448, 256, 0, stream>>>(KdE, KdO, u, ut);
  s4_conv     <<<2048, 256, 0, stream>>>(ut, KdE, KdO, D_skip);
  mfma_gemm_ln<<<1024, 256, 0, stream>>>(ut, Wbf, bias, u, gamma, beta, out);
}